// Round 7
// baseline (65.647 us; speedup 1.0000x reference)
//
#include <hip/hip_runtime.h>
#include <stdint.h>

#define NATOMS 4096
#define NCELLS 8000
#define KTOP 5
#define MNBR 8
#define NBRC 26
#define HBINS 217          // max histogram window: 4*(19*3)-11 = 217 bins
#define LSTMAX 512

__device__ __forceinline__ unsigned long long umax64(unsigned long long a, unsigned long long b) {
    return a > b ? a : b;
}
__device__ __forceinline__ unsigned long long umin64(unsigned long long a, unsigned long long b) {
    return a < b ? a : b;
}

// cells[m] = (g[b], g[c], g[a]) with m = a*400 + b*20 + c, g[t] = t-10
__device__ __forceinline__ void cell_coords_i(int m, int& x, int& y, int& z) {
    int a = m / 400;
    int r = m - a * 400;
    int b = r / 20;
    int c = r - b * 20;
    x = b - 10; y = c - 10; z = a - 10;
}

// ---------------------------------------------------------------------------
// Kernel 1 (fused): block b = atom b.
//  wave 0: analytic argmin cell over the 4x4x4 neighborhood of floor(atom)
//          (exact d^2 gap >= 1.0 >> f32 err; same f32 formula + min-key as
//          full scan -> bitwise identical) -> ci.
//  all waves: top-26 LARGEST cell-cell sq-dists for ci (tight per-cell
//          cutoff, windowed histogram -> cutoff V -> collect -> single-wave
//          rank-select, key (d desc, j asc) == jax.lax.top_k tie order).
//  Marks neededFlag[j]=1 WITHOUT pre-zeroing: marks are monotone (a false
//  positive only causes an extra correct-but-unused atomsInCells row), and
//  identical inputs each call -> stale marks coincide with fresh marks;
//  0xAA poison != 1. Safe with no zero pass.
// ---------------------------------------------------------------------------
__global__ __launch_bounds__(256) void k1_cells_nbr(const float* __restrict__ coords,
                                                    int* __restrict__ cellsForAtoms,
                                                    int* __restrict__ nbrTable,
                                                    int* __restrict__ neededFlag) {
    const int atom = blockIdx.x;
    const int t = threadIdx.x;
    const int lane = t & 63;

    __shared__ int sCi;
    __shared__ uint32_t h[HBINS];
    __shared__ int lst[LSTMAX];
    __shared__ int sV, cnt;

    if (t < HBINS) h[t] = 0;
    if (t == 0) cnt = 0;

    if (t < 64) {
        float ax = coords[atom * 3], ay = coords[atom * 3 + 1], az = coords[atom * 3 + 2];
        float sa = __fadd_rn(__fadd_rn(__fmul_rn(ax, ax), __fmul_rn(ay, ay)), __fmul_rn(az, az));

        int fx = (int)floorf(ax), fy = (int)floorf(ay), fz = (int)floorf(az);
        int vx = min(9, max(-10, fx - 1 + (lane & 3)));
        int vy = min(9, max(-10, fy - 1 + ((lane >> 2) & 3)));
        int vz = min(9, max(-10, fz - 1 + (lane >> 4)));
        int m = (vz + 10) * 400 + (vx + 10) * 20 + (vy + 10);

        float cx = (float)vx, cy = (float)vy, cz = (float)vz;
        float scell = (float)(vx * vx + vy * vy + vz * vz);
        float dot = __fadd_rn(__fadd_rn(__fmul_rn(ax, cx), __fmul_rn(ay, cy)), __fmul_rn(az, cz));
        float val = __fsub_rn(__fadd_rn(sa, scell), __fmul_rn(2.0f, dot));
        unsigned long long key = ((unsigned long long)__float_as_uint(val) << 32) | (unsigned int)m;

        for (int off = 32; off > 0; off >>= 1)
            key = umin64(key, (unsigned long long)__shfl_xor((long long)key, off));
        if (lane == 0) {
            int c = (int)(key & 0xFFFFFFFFull);
            cellsForAtoms[atom] = c;
            sCi = c;
        }
    }
    __syncthreads();

    const int ci = sCi;
    int xi, yi, zi;
    cell_coords_i(ci, xi, yi, zi);
    const int Lx = max(xi + 10, 9 - xi);
    const int Ly = max(yi + 10, 9 - yi);
    const int Lz = max(zi + 10, 9 - zi);
    const int lo = (Lx - 2) * (Lx - 2) + (Ly - 2) * (Ly - 2) + (Lz - 2) * (Lz - 2);

    // histogram pass: per-(b,c)-column analytic a-ranges with dz^2 >= lo-Dbc
#pragma unroll
    for (int col = 0; col < 2; ++col) {
        int p = t + 256 * col;
        if (p < 400) {
            int bb = p / 20, cc = p - bb * 20;
            int dxv = xi - (bb - 10), dyv = yi - (cc - 10);
            int Dbc = dxv * dxv + dyv * dyv;
            int R = lo - Dbc;
            int aLoEnd = 19, aHiStart = 20;
            if (R > 0) {
                int t0 = (int)ceilf(sqrtf((float)R));
                if ((t0 - 1) * (t0 - 1) >= R) --t0;
                if (t0 * t0 < R) ++t0;
                aLoEnd = min(19, zi + 10 - t0);
                aHiStart = max(0, zi + 10 + t0);
            }
            for (int a = 0; a <= aLoEnd; ++a) {
                int dzv = zi - (a - 10);
                atomicAdd(&h[Dbc + dzv * dzv - lo], 1u);
            }
            for (int a = aHiStart; a < 20; ++a) {
                int dzv = zi - (a - 10);
                atomicAdd(&h[Dbc + dzv * dzv - lo], 1u);
            }
        }
    }
    __syncthreads();

    // single-wave descending scan: V = largest value with suffix-count >= 26
    if (t < 64) {
        int c4[4];
        int cnt4 = 0;
#pragma unroll
        for (int k = 0; k < 4; ++k) {
            int b = (HBINS - 1) - (t * 4 + k);
            c4[k] = (b >= 0) ? (int)h[b] : 0;
            cnt4 += c4[k];
        }
        int incl = cnt4;
        for (int off = 1; off < 64; off <<= 1) {
            int v = __shfl_up(incl, off);
            if (lane >= off) incl += v;
        }
        int P = incl - cnt4;
        if (P < NBRC && incl >= NBRC) {
            int run = P;
#pragma unroll
            for (int k = 0; k < 4; ++k) {
                run += c4[k];
                if (run >= NBRC) { sV = lo + (HBINS - 1) - (t * 4 + k); break; }
            }
        }
    }
    __syncthreads();
    const int V = sV;

    // collect pass: all items with d >= V
#pragma unroll
    for (int col = 0; col < 2; ++col) {
        int p = t + 256 * col;
        if (p < 400) {
            int bb = p / 20, cc = p - bb * 20;
            int dxv = xi - (bb - 10), dyv = yi - (cc - 10);
            int Dbc = dxv * dxv + dyv * dyv;
            int R = V - Dbc;
            int aLoEnd = 19, aHiStart = 20;
            if (R > 0) {
                int t0 = (int)ceilf(sqrtf((float)R));
                if ((t0 - 1) * (t0 - 1) >= R) --t0;
                if (t0 * t0 < R) ++t0;
                aLoEnd = min(19, zi + 10 - t0);
                aHiStart = max(0, zi + 10 + t0);
            }
            for (int a = 0; a <= aLoEnd; ++a) {
                int dzv = zi - (a - 10);
                int d = Dbc + dzv * dzv;
                int j = a * 400 + p;
                int q = atomicAdd(&cnt, 1);
                if (q < LSTMAX) lst[q] = (d << 13) | (8191 - j);
            }
            for (int a = aHiStart; a < 20; ++a) {
                int dzv = zi - (a - 10);
                int d = Dbc + dzv * dzv;
                int j = a * 400 + p;
                int q = atomicAdd(&cnt, 1);
                if (q < LSTMAX) lst[q] = (d << 13) | (8191 - j);
            }
        }
    }
    __syncthreads();

    // single-wave rank selection: ranks 0..25 are the top-26 in key order
    int n = min(cnt, LSTMAX);
    if (t < 64) {
        for (int base = 0; base < n; base += 64) {
            int idx = base + t;
            int key = (idx < n) ? lst[idx] : -1;
            int rank = 0;
            for (int m = 0; m < n; ++m) rank += (lst[m] > key) ? 1 : 0;
            if (idx < n && rank < NBRC) {
                int j = 8191 - (key & 8191);
                nbrTable[ci * NBRC + rank] = j;
                neededFlag[j] = 1;
            }
        }
    }
}

// ---------------------------------------------------------------------------
// Kernel 2: atoms_in_cells = top-5 LARGEST atom distances for NEEDED cells.
// Also zeroes flagDone[0..1023] (consumed only by kernel 3 -> no race).
// ---------------------------------------------------------------------------
__global__ __launch_bounds__(256) void k2_atoms(const float* __restrict__ coords,
                                                const int* __restrict__ neededFlag,
                                                int* __restrict__ atomsInCells,
                                                int* __restrict__ flagDone) {
    const int i = blockIdx.x;
    if (threadIdx.x == 0 && i < 1024) flagDone[i] = 0;
    if (neededFlag[i] != 1) return;
    __shared__ unsigned long long redB[4];
    const int t = threadIdx.x;
    const int lane = t & 63, wv = t >> 6;

    int xi_, yi_, zi_;
    cell_coords_i(i, xi_, yi_, zi_);
    const float cx = (float)xi_, cy = (float)yi_, cz = (float)zi_;
    const float scell = (float)(xi_ * xi_ + yi_ * yi_ + zi_ * zi_);

    unsigned long long keys[16];
#pragma unroll
    for (int s = 0; s < 16; ++s) {
        int j = t + 256 * s;
        float ax = coords[j * 3], ay = coords[j * 3 + 1], az = coords[j * 3 + 2];
        float sa = __fadd_rn(__fadd_rn(__fmul_rn(ax, ax), __fmul_rn(ay, ay)), __fmul_rn(az, az));
        float dot = __fadd_rn(__fadd_rn(__fmul_rn(cx, ax), __fmul_rn(cy, ay)), __fmul_rn(cz, az));
        float val = __fsub_rn(__fadd_rn(scell, sa), __fmul_rn(2.0f, dot));
        keys[s] = ((unsigned long long)__float_as_uint(val) << 32) | (unsigned int)(4095 - j);
    }

    for (int r = 0; r < KTOP; ++r) {
        unsigned long long best = 0ull;
#pragma unroll
        for (int s = 0; s < 16; ++s) best = umax64(best, keys[s]);
        for (int off = 32; off > 0; off >>= 1)
            best = umax64(best, (unsigned long long)__shfl_xor((long long)best, off));
        if (lane == 0) redB[wv] = best;
        __syncthreads();
        unsigned long long wbest = umax64(umax64(redB[0], redB[1]), umax64(redB[2], redB[3]));
        if (t == 0) atomsInCells[i * KTOP + r] = 4095 - (int)(wbest & 0xFFFFFFFFull);
#pragma unroll
        for (int s = 0; s < 16; ++s) if (keys[s] == wbest) keys[s] = 0ull;
        __syncthreads();
    }
}

// ---------------------------------------------------------------------------
// Kernel 3 (fused energy + reduction): grid 1025.
//  blocks 0..1023: 4 atoms each (one per wave): gather 130 candidates, top-8
//    LARGEST (tie: lower flat position), energy partial -> plain store; then
//    release-store flagDone[b]=1.
//  block 1024: acquire-poll all 1024 flags (loads only, no RMW -> no line
//    ping-pong), then the SAME deterministic tree reduction + division.
//  All 1025 blocks fit co-resident (capacity ~2048) -> no deadlock.
// ---------------------------------------------------------------------------
__global__ __launch_bounds__(256) void k3_energy_red(const float* __restrict__ coords,
                                                     const float* __restrict__ vdw,
                                                     const float* __restrict__ weights,
                                                     const float* __restrict__ nrot,
                                                     const int* __restrict__ nbrTable,
                                                     const int* __restrict__ atomsInCells,
                                                     const int* __restrict__ cellsForAtoms,
                                                     float* __restrict__ partials,
                                                     int* __restrict__ flagDone,
                                                     float* __restrict__ out) {
    __shared__ float red[256];
    const int t = threadIdx.x;

    if (blockIdx.x == 1024) {
        // reducer block: wait for all data blocks, then deterministic reduce
        for (int k = 0; k < 4; ++k) {
            int f = t * 4 + k;
            while (__hip_atomic_load(&flagDone[f], __ATOMIC_ACQUIRE,
                                     __HIP_MEMORY_SCOPE_AGENT) != 1) {
                __builtin_amdgcn_s_sleep(8);
            }
        }
        __syncthreads();
        float s = 0.0f;
        for (int k = 0; k < NATOMS / 256; ++k) s = __fadd_rn(s, partials[t + 256 * k]);
        red[t] = s;
        __syncthreads();
        for (int off = 128; off > 0; off >>= 1) {
            if (t < off) red[t] = __fadd_rn(red[t], red[t + off]);
            __syncthreads();
        }
        if (t == 0) out[0] = __fdiv_rn(red[0], __fadd_rn(1.0f, __fmul_rn(weights[5], nrot[0])));
        return;
    }

    const int wid = t >> 6;
    const int lane = t & 63;
    const int i = blockIdx.x * 4 + wid;

    const float xi = coords[i * 3], yi = coords[i * 3 + 1], zi = coords[i * 3 + 2];
    const int ci = cellsForAtoms[i];

    int cand[3];
    unsigned long long keys[3];
#pragma unroll
    for (int s = 0; s < 3; ++s) {
        int p = lane + 64 * s;
        cand[s] = -1;
        keys[s] = 0ull;
        if (p < NBRC * KTOP) {
            int cellSlot = p / KTOP;
            int atomSlot = p - cellSlot * KTOP;
            int nc = nbrTable[ci * NBRC + cellSlot];
            int j = atomsInCells[nc * KTOP + atomSlot];
            cand[s] = j;
            float dx = __fsub_rn(xi, coords[j * 3]);
            float dy = __fsub_rn(yi, coords[j * 3 + 1]);
            float dz = __fsub_rn(zi, coords[j * 3 + 2]);
            float dist = __fadd_rn(__fadd_rn(__fmul_rn(dx, dx), __fmul_rn(dy, dy)), __fmul_rn(dz, dz));
            keys[s] = ((unsigned long long)__float_as_uint(dist) << 8) | (unsigned int)(255 - p);
        }
    }

    const float w0 = weights[0], w1 = weights[1], w2 = weights[2];
    const float w3 = weights[3], w4 = weights[4];
    const float vi = vdw[i];

    float esum = 0.0f;
    for (int r = 0; r < MNBR; ++r) {
        unsigned long long best = umax64(umax64(keys[0], keys[1]), keys[2]);
        for (int off = 32; off > 0; off >>= 1)
            best = umax64(best, (unsigned long long)__shfl_xor((long long)best, off));

        int p = 255 - (int)(best & 0xFFull);
        int slot = p >> 6;
        int owner = p & 63;
        int jsel = (slot == 0) ? cand[0] : (slot == 1) ? cand[1] : cand[2];
        int j = __shfl(jsel, owner);
        float dist = __uint_as_float((unsigned int)(best >> 8));

#pragma unroll
        for (int s = 0; s < 3; ++s) if (keys[s] == best) keys[s] = 0ull;

        float rr = __fsqrt_rn(__fadd_rn(dist, 1e-12f));
        float d = __fsub_rn(__fsub_rn(rr, vi), vdw[j]);
        float t1 = __fdiv_rn(d, 0.5f);
        float g1 = expf(-__fmul_rn(t1, t1));
        float t2 = __fdiv_rn(__fsub_rn(d, 3.0f), 2.0f);
        float g2 = expf(-__fmul_rn(t2, t2));
        float rep = (d < 0.0f) ? __fmul_rn(d, d) : 0.0f;
        float hyd = (d < 0.5f) ? 1.0f : ((d < 1.5f) ? __fsub_rn(1.5f, d) : 0.0f);
        float hb = (d < -0.7f) ? 1.0f : ((d < 0.0f) ? __fdiv_rn(-d, 0.7f) : 0.0f);
        float hval = __fadd_rn(__fadd_rn(__fadd_rn(__fadd_rn(
                         __fmul_rn(w0, g1), __fmul_rn(w1, g2)),
                         __fmul_rn(w2, rep)), __fmul_rn(w3, hyd)), __fmul_rn(w4, hb));
        float f = (d < 8.0f) ? hval : 0.0f;
        esum = __fadd_rn(esum, f);
    }
    if (lane == 0) partials[i] = esum;

    __syncthreads();
    if (t == 0) {
        __threadfence();
        __hip_atomic_store(&flagDone[blockIdx.x], 1, __ATOMIC_RELEASE,
                           __HIP_MEMORY_SCOPE_AGENT);
    }
}

extern "C" void kernel_launch(void* const* d_in, const int* in_sizes, int n_in,
                              void* d_out, int out_size, void* d_ws, size_t ws_size,
                              hipStream_t stream) {
    const float* coords  = (const float*)d_in[0];
    const float* vdw     = (const float*)d_in[1];
    const float* weights = (const float*)d_in[2];
    const float* nrot    = (const float*)d_in[3];
    float* out = (float*)d_out;

    int* nbrTable      = (int*)d_ws;                       // 208000
    int* atomsInCells  = nbrTable + NCELLS * NBRC;         // 40000
    int* cellsForAtoms = atomsInCells + NCELLS * KTOP;     // 4096
    int* neededFlag    = cellsForAtoms + NATOMS;           // 8000
    int* flagDone      = neededFlag + NCELLS;              // 1024
    float* partials    = (float*)(flagDone + 1024);        // 4096

    k1_cells_nbr<<<NATOMS, 256, 0, stream>>>(coords, cellsForAtoms, nbrTable, neededFlag);
    k2_atoms<<<NCELLS, 256, 0, stream>>>(coords, neededFlag, atomsInCells, flagDone);
    k3_energy_red<<<1025, 256, 0, stream>>>(coords, vdw, weights, nrot, nbrTable,
                                            atomsInCells, cellsForAtoms, partials,
                                            flagDone, out);
}

// Round 8
// 42.558 us; speedup vs baseline: 1.5425x; 1.5425x over previous
//
#include <hip/hip_runtime.h>
#include <stdint.h>

#define NATOMS 4096
#define NCELLS 8000
#define KTOP 5
#define MNBR 8
#define NBRC 26
#define HBINS 217          // max histogram window (proof: window <= 4*3*19-11)
#define LSTMAX 512

__device__ __forceinline__ unsigned long long umax64(unsigned long long a, unsigned long long b) {
    return a > b ? a : b;
}
__device__ __forceinline__ unsigned long long umin64(unsigned long long a, unsigned long long b) {
    return a < b ? a : b;
}

// cells[m] = (g[b], g[c], g[a]) with m = a*400 + b*20 + c, g[t] = t-10
__device__ __forceinline__ void cell_coords_i(int m, int& x, int& y, int& z) {
    int a = m / 400;
    int r = m - a * 400;
    int b = r / 20;
    int c = r - b * 20;
    x = b - 10; y = c - 10; z = a - 10;
}

// ---------------------------------------------------------------------------
// Kernel 1 (fused): block b = atom b.
//  wave 0: analytic argmin cell over the 4x4x4 neighborhood of floor(atom)
//          (exact d^2 gap >= 1.0 >> f32 err; same f32 formula + min-key as
//          the full scan -> bitwise identical) -> ci.
//  all waves: top-26 LARGEST cell-cell sq-dists for ci. lo = 2nd-smallest of
//          the 27 combos (Lx-kx)^2+(Ly-ky)^2+(Lz-kz)^2, k in {0,1,2}^3 — an
//          exact lower bound on the 26th-largest d^2 (26 distinct cells have
//          d^2 >= lo). Windowed histogram -> cutoff V -> collect d>=V ->
//          single-wave rank-select, key (d desc, j asc) == top_k tie order.
//  neededFlag marks are monotone + inputs identical across calls -> no
//  pre-zeroing needed (poison 0xAA != 1; stale 1s coincide with fresh marks).
// ---------------------------------------------------------------------------
__global__ __launch_bounds__(256) void k1_cells_nbr(const float* __restrict__ coords,
                                                    int* __restrict__ cellsForAtoms,
                                                    int* __restrict__ nbrTable,
                                                    int* __restrict__ neededFlag) {
    const int atom = blockIdx.x;
    const int t = threadIdx.x;
    const int lane = t & 63;

    __shared__ int sCi;
    __shared__ uint32_t h[HBINS];
    __shared__ int lst[LSTMAX];
    __shared__ int sV, cnt;

    if (t < HBINS) h[t] = 0;
    if (t == 0) cnt = 0;

    if (t < 64) {
        float ax = coords[atom * 3], ay = coords[atom * 3 + 1], az = coords[atom * 3 + 2];
        float sa = __fadd_rn(__fadd_rn(__fmul_rn(ax, ax), __fmul_rn(ay, ay)), __fmul_rn(az, az));

        int fx = (int)floorf(ax), fy = (int)floorf(ay), fz = (int)floorf(az);
        int vx = min(9, max(-10, fx - 1 + (lane & 3)));
        int vy = min(9, max(-10, fy - 1 + ((lane >> 2) & 3)));
        int vz = min(9, max(-10, fz - 1 + (lane >> 4)));
        int m = (vz + 10) * 400 + (vx + 10) * 20 + (vy + 10);

        float cx = (float)vx, cy = (float)vy, cz = (float)vz;
        float scell = (float)(vx * vx + vy * vy + vz * vz);
        float dot = __fadd_rn(__fadd_rn(__fmul_rn(ax, cx), __fmul_rn(ay, cy)), __fmul_rn(az, cz));
        float val = __fsub_rn(__fadd_rn(sa, scell), __fmul_rn(2.0f, dot));
        unsigned long long key = ((unsigned long long)__float_as_uint(val) << 32) | (unsigned int)m;

        for (int off = 32; off > 0; off >>= 1)
            key = umin64(key, (unsigned long long)__shfl_xor((long long)key, off));
        if (lane == 0) {
            int c = (int)(key & 0xFFFFFFFFull);
            cellsForAtoms[atom] = c;
            sCi = c;
        }
    }
    __syncthreads();

    const int ci = sCi;
    int xi, yi, zi;
    cell_coords_i(ci, xi, yi, zi);
    const int Lx = max(xi + 10, 9 - xi);
    const int Ly = max(yi + 10, 9 - yi);
    const int Lz = max(zi + 10, 9 - zi);

    // lo = 2nd-smallest of the 27 combo sums (uniform per-thread compute)
    int lo;
    {
        int px[3] = { Lx * Lx, (Lx - 1) * (Lx - 1), (Lx - 2) * (Lx - 2) };
        int py[3] = { Ly * Ly, (Ly - 1) * (Ly - 1), (Ly - 2) * (Ly - 2) };
        int pz[3] = { Lz * Lz, (Lz - 1) * (Lz - 1), (Lz - 2) * (Lz - 2) };
        int m1 = 0x7FFFFFFF, m2 = 0x7FFFFFFF;   // two smallest
#pragma unroll
        for (int a = 0; a < 3; ++a)
#pragma unroll
            for (int b = 0; b < 3; ++b)
#pragma unroll
                for (int c = 0; c < 3; ++c) {
                    int s = px[a] + py[b] + pz[c];
                    if (s < m1) { m2 = m1; m1 = s; }
                    else if (s < m2) m2 = s;
                }
        lo = m2;
    }

    // histogram pass: per-(b,c)-column analytic a-ranges with dz^2 >= lo-Dbc
#pragma unroll
    for (int col = 0; col < 2; ++col) {
        int p = t + 256 * col;
        if (p < 400) {
            int bb = p / 20, cc = p - bb * 20;
            int dxv = xi - (bb - 10), dyv = yi - (cc - 10);
            int Dbc = dxv * dxv + dyv * dyv;
            int R = lo - Dbc;
            int aLoEnd = 19, aHiStart = 20;
            if (R > 0) {
                int t0 = (int)ceilf(sqrtf((float)R));
                if ((t0 - 1) * (t0 - 1) >= R) --t0;
                if (t0 * t0 < R) ++t0;
                aLoEnd = min(19, zi + 10 - t0);
                aHiStart = max(0, zi + 10 + t0);
            }
            for (int a = 0; a <= aLoEnd; ++a) {
                int dzv = zi - (a - 10);
                atomicAdd(&h[Dbc + dzv * dzv - lo], 1u);
            }
            for (int a = aHiStart; a < 20; ++a) {
                int dzv = zi - (a - 10);
                atomicAdd(&h[Dbc + dzv * dzv - lo], 1u);
            }
        }
    }
    __syncthreads();

    // single-wave descending scan: V = largest value with suffix-count >= 26
    if (t < 64) {
        int c4[4];
        int cnt4 = 0;
#pragma unroll
        for (int k = 0; k < 4; ++k) {
            int b = (HBINS - 1) - (t * 4 + k);
            c4[k] = (b >= 0) ? (int)h[b] : 0;
            cnt4 += c4[k];
        }
        int incl = cnt4;
        for (int off = 1; off < 64; off <<= 1) {
            int v = __shfl_up(incl, off);
            if (lane >= off) incl += v;
        }
        int P = incl - cnt4;
        if (P < NBRC && incl >= NBRC) {
            int run = P;
#pragma unroll
            for (int k = 0; k < 4; ++k) {
                run += c4[k];
                if (run >= NBRC) { sV = lo + (HBINS - 1) - (t * 4 + k); break; }
            }
        }
    }
    __syncthreads();
    const int V = sV;

    // collect pass: all items with d >= V
#pragma unroll
    for (int col = 0; col < 2; ++col) {
        int p = t + 256 * col;
        if (p < 400) {
            int bb = p / 20, cc = p - bb * 20;
            int dxv = xi - (bb - 10), dyv = yi - (cc - 10);
            int Dbc = dxv * dxv + dyv * dyv;
            int R = V - Dbc;
            int aLoEnd = 19, aHiStart = 20;
            if (R > 0) {
                int t0 = (int)ceilf(sqrtf((float)R));
                if ((t0 - 1) * (t0 - 1) >= R) --t0;
                if (t0 * t0 < R) ++t0;
                aLoEnd = min(19, zi + 10 - t0);
                aHiStart = max(0, zi + 10 + t0);
            }
            for (int a = 0; a <= aLoEnd; ++a) {
                int dzv = zi - (a - 10);
                int d = Dbc + dzv * dzv;
                int j = a * 400 + p;
                int q = atomicAdd(&cnt, 1);
                if (q < LSTMAX) lst[q] = (d << 13) | (8191 - j);
            }
            for (int a = aHiStart; a < 20; ++a) {
                int dzv = zi - (a - 10);
                int d = Dbc + dzv * dzv;
                int j = a * 400 + p;
                int q = atomicAdd(&cnt, 1);
                if (q < LSTMAX) lst[q] = (d << 13) | (8191 - j);
            }
        }
    }
    __syncthreads();

    // single-wave rank selection: ranks 0..25 are the top-26 in key order
    int n = min(cnt, LSTMAX);
    if (t < 64) {
        for (int base = 0; base < n; base += 64) {
            int idx = base + t;
            int key = (idx < n) ? lst[idx] : -1;
            int rank = 0;
            for (int m = 0; m < n; ++m) rank += (lst[m] > key) ? 1 : 0;
            if (idx < n && rank < NBRC) {
                int j = 8191 - (key & 8191);
                nbrTable[ci * NBRC + rank] = j;
                neededFlag[j] = 1;
            }
        }
    }
}

// ---------------------------------------------------------------------------
// Kernel 2: atoms_in_cells = top-5 LARGEST atom distances for NEEDED cells.
// ---------------------------------------------------------------------------
__global__ __launch_bounds__(256) void k2_atoms(const float* __restrict__ coords,
                                                const int* __restrict__ neededFlag,
                                                int* __restrict__ atomsInCells) {
    const int i = blockIdx.x;
    if (neededFlag[i] != 1) return;
    __shared__ unsigned long long redB[4];
    const int t = threadIdx.x;
    const int lane = t & 63, wv = t >> 6;

    int xi_, yi_, zi_;
    cell_coords_i(i, xi_, yi_, zi_);
    const float cx = (float)xi_, cy = (float)yi_, cz = (float)zi_;
    const float scell = (float)(xi_ * xi_ + yi_ * yi_ + zi_ * zi_);

    unsigned long long keys[16];
#pragma unroll
    for (int s = 0; s < 16; ++s) {
        int j = t + 256 * s;
        float ax = coords[j * 3], ay = coords[j * 3 + 1], az = coords[j * 3 + 2];
        float sa = __fadd_rn(__fadd_rn(__fmul_rn(ax, ax), __fmul_rn(ay, ay)), __fmul_rn(az, az));
        float dot = __fadd_rn(__fadd_rn(__fmul_rn(cx, ax), __fmul_rn(cy, ay)), __fmul_rn(cz, az));
        float val = __fsub_rn(__fadd_rn(scell, sa), __fmul_rn(2.0f, dot));
        keys[s] = ((unsigned long long)__float_as_uint(val) << 32) | (unsigned int)(4095 - j);
    }

    for (int r = 0; r < KTOP; ++r) {
        unsigned long long best = 0ull;
#pragma unroll
        for (int s = 0; s < 16; ++s) best = umax64(best, keys[s]);
        for (int off = 32; off > 0; off >>= 1)
            best = umax64(best, (unsigned long long)__shfl_xor((long long)best, off));
        if (lane == 0) redB[wv] = best;
        __syncthreads();
        unsigned long long wbest = umax64(umax64(redB[0], redB[1]), umax64(redB[2], redB[3]));
        if (t == 0) atomsInCells[i * KTOP + r] = 4095 - (int)(wbest & 0xFFFFFFFFull);
#pragma unroll
        for (int s = 0; s < 16; ++s) if (keys[s] == wbest) keys[s] = 0ull;
        __syncthreads();
    }
}

// ---------------------------------------------------------------------------
// Kernel 3: per-atom gather of 130 candidates, top-8 LARGEST (tie: lower
// flat position), then energy partial -> plain store (NO atomics, NO fences).
// ---------------------------------------------------------------------------
__global__ __launch_bounds__(256) void k3_energy(const float* __restrict__ coords,
                                                 const float* __restrict__ vdw,
                                                 const float* __restrict__ weights,
                                                 const int* __restrict__ nbrTable,
                                                 const int* __restrict__ atomsInCells,
                                                 const int* __restrict__ cellsForAtoms,
                                                 float* __restrict__ partials) {
    const int wid = threadIdx.x >> 6;
    const int lane = threadIdx.x & 63;
    const int i = blockIdx.x * 4 + wid;

    const float xi = coords[i * 3], yi = coords[i * 3 + 1], zi = coords[i * 3 + 2];
    const int ci = cellsForAtoms[i];

    int cand[3];
    unsigned long long keys[3];
#pragma unroll
    for (int s = 0; s < 3; ++s) {
        int p = lane + 64 * s;
        cand[s] = -1;
        keys[s] = 0ull;
        if (p < NBRC * KTOP) {
            int cellSlot = p / KTOP;
            int atomSlot = p - cellSlot * KTOP;
            int nc = nbrTable[ci * NBRC + cellSlot];
            int j = atomsInCells[nc * KTOP + atomSlot];
            cand[s] = j;
            float dx = __fsub_rn(xi, coords[j * 3]);
            float dy = __fsub_rn(yi, coords[j * 3 + 1]);
            float dz = __fsub_rn(zi, coords[j * 3 + 2]);
            float dist = __fadd_rn(__fadd_rn(__fmul_rn(dx, dx), __fmul_rn(dy, dy)), __fmul_rn(dz, dz));
            keys[s] = ((unsigned long long)__float_as_uint(dist) << 8) | (unsigned int)(255 - p);
        }
    }

    const float w0 = weights[0], w1 = weights[1], w2 = weights[2];
    const float w3 = weights[3], w4 = weights[4];
    const float vi = vdw[i];

    float esum = 0.0f;
    for (int r = 0; r < MNBR; ++r) {
        unsigned long long best = umax64(umax64(keys[0], keys[1]), keys[2]);
        for (int off = 32; off > 0; off >>= 1)
            best = umax64(best, (unsigned long long)__shfl_xor((long long)best, off));

        int p = 255 - (int)(best & 0xFFull);
        int slot = p >> 6;
        int owner = p & 63;
        int jsel = (slot == 0) ? cand[0] : (slot == 1) ? cand[1] : cand[2];
        int j = __shfl(jsel, owner);
        float dist = __uint_as_float((unsigned int)(best >> 8));

#pragma unroll
        for (int s = 0; s < 3; ++s) if (keys[s] == best) keys[s] = 0ull;

        float rr = __fsqrt_rn(__fadd_rn(dist, 1e-12f));
        float d = __fsub_rn(__fsub_rn(rr, vi), vdw[j]);
        float t1 = __fdiv_rn(d, 0.5f);
        float g1 = expf(-__fmul_rn(t1, t1));
        float t2 = __fdiv_rn(__fsub_rn(d, 3.0f), 2.0f);
        float g2 = expf(-__fmul_rn(t2, t2));
        float rep = (d < 0.0f) ? __fmul_rn(d, d) : 0.0f;
        float hyd = (d < 0.5f) ? 1.0f : ((d < 1.5f) ? __fsub_rn(1.5f, d) : 0.0f);
        float hb = (d < -0.7f) ? 1.0f : ((d < 0.0f) ? __fdiv_rn(-d, 0.7f) : 0.0f);
        float hval = __fadd_rn(__fadd_rn(__fadd_rn(__fadd_rn(
                         __fmul_rn(w0, g1), __fmul_rn(w1, g2)),
                         __fmul_rn(w2, rep)), __fmul_rn(w3, hyd)), __fmul_rn(w4, hb));
        float f = (d < 8.0f) ? hval : 0.0f;
        esum = __fadd_rn(esum, f);
    }
    if (lane == 0) partials[i] = esum;
}

// ---------------------------------------------------------------------------
// Kernel 4: deterministic tree reduction + final division.
// ---------------------------------------------------------------------------
__global__ __launch_bounds__(256) void k4_reduce(const float* __restrict__ partials,
                                                 const float* __restrict__ weights,
                                                 const float* __restrict__ nrot,
                                                 float* __restrict__ out) {
    __shared__ float red[256];
    const int t = threadIdx.x;
    float s = 0.0f;
    for (int k = 0; k < NATOMS / 256; ++k) s = __fadd_rn(s, partials[t + 256 * k]);
    red[t] = s;
    __syncthreads();
    for (int off = 128; off > 0; off >>= 1) {
        if (t < off) red[t] = __fadd_rn(red[t], red[t + off]);
        __syncthreads();
    }
    if (t == 0) out[0] = __fdiv_rn(red[0], __fadd_rn(1.0f, __fmul_rn(weights[5], nrot[0])));
}

extern "C" void kernel_launch(void* const* d_in, const int* in_sizes, int n_in,
                              void* d_out, int out_size, void* d_ws, size_t ws_size,
                              hipStream_t stream) {
    const float* coords  = (const float*)d_in[0];
    const float* vdw     = (const float*)d_in[1];
    const float* weights = (const float*)d_in[2];
    const float* nrot    = (const float*)d_in[3];
    float* out = (float*)d_out;

    int* nbrTable      = (int*)d_ws;                       // 208000
    int* atomsInCells  = nbrTable + NCELLS * NBRC;         // 40000
    int* cellsForAtoms = atomsInCells + NCELLS * KTOP;     // 4096
    int* neededFlag    = cellsForAtoms + NATOMS;           // 8000
    float* partials    = (float*)(neededFlag + NCELLS);    // 4096

    k1_cells_nbr<<<NATOMS, 256, 0, stream>>>(coords, cellsForAtoms, nbrTable, neededFlag);
    k2_atoms<<<NCELLS, 256, 0, stream>>>(coords, neededFlag, atomsInCells);
    k3_energy<<<NATOMS / 4, 256, 0, stream>>>(coords, vdw, weights, nbrTable,
                                              atomsInCells, cellsForAtoms, partials);
    k4_reduce<<<1, 256, 0, stream>>>(partials, weights, nrot, out);
}